// Round 2
// baseline (5292.426 us; speedup 1.0000x reference)
//
#include <hip/hip_runtime.h>

// Linear RNN: h_0 = initial + proj[0]; h_t = h_{t-1} @ Whh^T + proj[t-1], t=1..T-1
// out = (hidden, hidden) concatenated, hidden[n][t][j] fp32.
//
// Design (round 1, pure fp32 — tolerance is ~2% rel but bf16 Whh would blow up
// the dominant eigenvalue; fp32 gives ~1e-4 rel, huge margin):
//  K0: proj GEMM, stored SHIFTED: B[t] = proj[max(t-1,0)] into d_out half B.
//  K1: phase1 — 256 chunks x 16 steps, one block/CU, local scan (zero init),
//      chunk-final z_c -> ws.  [R1 FIX: local scan starts at t0+1 — init value
//      B[t0] IS the local state at t0; looping from t0 did one extra W-step.]
//  K2: 11 squarings W^2..W^2048 (stored in tail of d_out half A — dead space
//      until phase 3 overwrites it AFTER all reads).
//  K3: 8 Kogge-Stone rounds over 256 boundary states (ping-pong in ws, 16 MB).
//  K4: phase3 — re-run chunks from true boundary states, write both halves.
// All launches on `stream`; no malloc/sync; same work every call.

constexpr int NN = 16;
constexpr int TT = 4096;
constexpr int II = 256;
constexpr int HH = 512;
constexpr int CK = 16;                 // steps per chunk
constexpr int NC = 256;                // chunks
constexpr long NTH = (long)NN * TT * HH;   // 33,554,432 floats per output half
constexpr int NMATS = 11;              // W^2 .. W^2048

// ---------------------------------------------------------------- proj ------
// B[n][t][j] = bi[j] + sum_i x[n][max(t-1,0)][i] * Wi[j][i]
// grid (TT/32, HH/128, NN), block 256
__global__ __launch_bounds__(256) void proj_kernel(
    const float* __restrict__ x, const float* __restrict__ Wi,
    const float* __restrict__ bi, float* __restrict__ Bh)
{
    const int t0 = blockIdx.x * 32;
    const int j0 = blockIdx.y * 128;
    const int n  = blockIdx.z;
    __shared__ __align__(16) float xs[32][II];   // 32 KB

    {   // stage 32 x-rows (with t-1 shift, clamped)
        const int r  = threadIdx.x >> 3;
        const int ci = threadIdx.x & 7;
        int s = t0 + r - 1; if (s < 0) s = 0;
        const float4* src = (const float4*)(x + ((size_t)n * TT + s) * II);
        float4* drow = (float4*)xs[r];
#pragma unroll
        for (int q = 0; q < 8; q++) drow[ci + 8 * q] = src[ci + 8 * q];
    }
    __syncthreads();

    const int tj  = threadIdx.x & 31;   // j-quad
    const int tt4 = threadIdx.x >> 5;   // t-quad (0..7)
    const int j   = j0 + tj * 4;

    float c0[4] = {0,0,0,0}, c1[4] = {0,0,0,0}, c2[4] = {0,0,0,0}, c3[4] = {0,0,0,0};
    for (int i = 0; i < II; i += 4) {
        float4 w0 = *(const float4*)(Wi + (size_t)(j + 0) * II + i);
        float4 w1 = *(const float4*)(Wi + (size_t)(j + 1) * II + i);
        float4 w2 = *(const float4*)(Wi + (size_t)(j + 2) * II + i);
        float4 w3 = *(const float4*)(Wi + (size_t)(j + 3) * II + i);
#pragma unroll
        for (int a = 0; a < 4; a++) {
            float4 xv = *(const float4*)(&xs[tt4 * 4 + a][i]);
            c0[a] = fmaf(xv.x, w0.x, c0[a]); c0[a] = fmaf(xv.y, w0.y, c0[a]);
            c0[a] = fmaf(xv.z, w0.z, c0[a]); c0[a] = fmaf(xv.w, w0.w, c0[a]);
            c1[a] = fmaf(xv.x, w1.x, c1[a]); c1[a] = fmaf(xv.y, w1.y, c1[a]);
            c1[a] = fmaf(xv.z, w1.z, c1[a]); c1[a] = fmaf(xv.w, w1.w, c1[a]);
            c2[a] = fmaf(xv.x, w2.x, c2[a]); c2[a] = fmaf(xv.y, w2.y, c2[a]);
            c2[a] = fmaf(xv.z, w2.z, c2[a]); c2[a] = fmaf(xv.w, w2.w, c2[a]);
            c3[a] = fmaf(xv.x, w3.x, c3[a]); c3[a] = fmaf(xv.y, w3.y, c3[a]);
            c3[a] = fmaf(xv.z, w3.z, c3[a]); c3[a] = fmaf(xv.w, w3.w, c3[a]);
        }
    }
    const float4 bv = *(const float4*)(bi + j);
#pragma unroll
    for (int a = 0; a < 4; a++) {
        const int t = t0 + tt4 * 4 + a;
        float4 o = make_float4(c0[a] + bv.x, c1[a] + bv.y, c2[a] + bv.z, c3[a] + bv.w);
        *(float4*)(Bh + ((size_t)n * TT + t) * HH + j) = o;
    }
}

// ---------------------------------------------------------- phase 1 / 3 -----
// One block per chunk, 256 threads: thread = (jh 0..127 -> 4 cols, nh 0..1 -> 8 rows)
// PHASE==1: local scan from zero (chunk 0: from initial+B[0]), z_c -> Zout.
// PHASE==3: scan from true boundary Gin[c-1], write h to outA and Bh slots.
template <int PHASE>
__global__ __launch_bounds__(256) void phase_kernel(
    const float* __restrict__ W,      // Whh [H][H]
    float* __restrict__ Bh,           // half B (B values; phase3 overwrites with h)
    const float* __restrict__ init_,  // initial [N][H]
    const float* __restrict__ Gin,    // boundary states [NC][N][H]
    float* __restrict__ Zout,         // chunk-final local states [NC][N][H]
    float* __restrict__ outA)         // half A
{
    __shared__ __align__(16) float h[2][NN][HH];   // 64 KB ping-pong
    const int c   = blockIdx.x;
    const int tid = threadIdx.x;
    const int jh  = tid & 127;
    const int j   = jh * 4;
    const int nh  = tid >> 7;
    const int n0  = nh * 8;

    int cur = 0;
    if (c == 0) {
#pragma unroll
        for (int a = 0; a < 8; a++) {
            const int n = n0 + a;
            float4 iv = *(const float4*)(init_ + (size_t)n * HH + j);
            float4 bv = *(const float4*)(Bh + (size_t)n * TT * HH + j);
            float4 o  = make_float4(iv.x + bv.x, iv.y + bv.y, iv.z + bv.z, iv.w + bv.w);
            *(float4*)(&h[0][n][j]) = o;
            if (PHASE == 3) {
                *(float4*)(outA + (size_t)n * TT * HH + j) = o;
                *(float4*)(Bh   + (size_t)n * TT * HH + j) = o;
            }
        }
    } else if (PHASE == 1) {
        const int t0 = c * CK;
#pragma unroll
        for (int a = 0; a < 8; a++) {
            const int n = n0 + a;
            *(float4*)(&h[0][n][j]) =
                *(const float4*)(Bh + ((size_t)n * TT + t0) * HH + j);
        }
    } else {
#pragma unroll
        for (int a = 0; a < 8; a++) {
            const int n = n0 + a;
            *(float4*)(&h[0][n][j]) =
                *(const float4*)(Gin + (size_t)(c - 1) * NN * HH + (size_t)n * HH + j);
        }
    }
    __syncthreads();

    // PHASE 1: init value IS the local state at t0 (incoming state is zero),
    // so the loop starts at t0+1 (R1 fix — looping from t0 did an extra step).
    // PHASE 3: init value is the state at t0-1 (true boundary), loop from t0.
    const int tstart = (PHASE == 1) ? (c * CK + 1)
                                    : ((c == 0) ? 1 : c * CK);
    const int tend   = c * CK + CK;
    const float* Wr0 = W + (size_t)(j + 0) * HH;
    const float* Wr1 = W + (size_t)(j + 1) * HH;
    const float* Wr2 = W + (size_t)(j + 2) * HH;
    const float* Wr3 = W + (size_t)(j + 3) * HH;

    for (int t = tstart; t < tend; t++) {
        float acc0[8], acc1[8], acc2[8], acc3[8];
#pragma unroll
        for (int a = 0; a < 8; a++) { acc0[a] = 0.f; acc1[a] = 0.f; acc2[a] = 0.f; acc3[a] = 0.f; }

        for (int k = 0; k < HH; k += 4) {
            float4 w0 = *(const float4*)(Wr0 + k);
            float4 w1 = *(const float4*)(Wr1 + k);
            float4 w2 = *(const float4*)(Wr2 + k);
            float4 w3 = *(const float4*)(Wr3 + k);
#pragma unroll
            for (int a = 0; a < 8; a++) {
                float4 hv = *(const float4*)(&h[cur][n0 + a][k]);
                acc0[a] = fmaf(hv.x, w0.x, acc0[a]); acc0[a] = fmaf(hv.y, w0.y, acc0[a]);
                acc0[a] = fmaf(hv.z, w0.z, acc0[a]); acc0[a] = fmaf(hv.w, w0.w, acc0[a]);
                acc1[a] = fmaf(hv.x, w1.x, acc1[a]); acc1[a] = fmaf(hv.y, w1.y, acc1[a]);
                acc1[a] = fmaf(hv.z, w1.z, acc1[a]); acc1[a] = fmaf(hv.w, w1.w, acc1[a]);
                acc2[a] = fmaf(hv.x, w2.x, acc2[a]); acc2[a] = fmaf(hv.y, w2.y, acc2[a]);
                acc2[a] = fmaf(hv.z, w2.z, acc2[a]); acc2[a] = fmaf(hv.w, w2.w, acc2[a]);
                acc3[a] = fmaf(hv.x, w3.x, acc3[a]); acc3[a] = fmaf(hv.y, w3.y, acc3[a]);
                acc3[a] = fmaf(hv.z, w3.z, acc3[a]); acc3[a] = fmaf(hv.w, w3.w, acc3[a]);
            }
        }

        const int nxt = cur ^ 1;
#pragma unroll
        for (int a = 0; a < 8; a++) {
            const int n = n0 + a;
            float* bp = Bh + ((size_t)n * TT + t) * HH + j;
            float4 bv = *(const float4*)bp;
            float4 o  = make_float4(acc0[a] + bv.x, acc1[a] + bv.y,
                                    acc2[a] + bv.z, acc3[a] + bv.w);
            *(float4*)(&h[nxt][n][j]) = o;
            if (PHASE == 3) {
                *(float4*)(outA + ((size_t)n * TT + t) * HH + j) = o;
                *(float4*)bp = o;
            }
        }
        __syncthreads();
        cur = nxt;
    }

    if (PHASE == 1) {
#pragma unroll
        for (int a = 0; a < 8; a++) {
            const int n = n0 + a;
            *(float4*)(Zout + (size_t)c * NN * HH + (size_t)n * HH + j) =
                *(const float4*)(&h[cur][n][j]);
        }
    }
}

// ----------------------------------------------------------- squaring -------
// Out = A @ A, 512x512 row-major. grid (4, 32): 128-col slice x 16-row slice.
__global__ __launch_bounds__(256) void sq_kernel(
    const float* __restrict__ A, float* __restrict__ Out)
{
    const int j0 = blockIdx.x * 128;
    const int a0 = blockIdx.y * 16;
    __shared__ __align__(16) float As[16][HH];   // 32 KB
    {
        const float4* src = (const float4*)(A + (size_t)a0 * HH);
        float4* d = (float4*)As;
#pragma unroll
        for (int r = 0; r < 8; r++) d[threadIdx.x + r * 256] = src[threadIdx.x + r * 256];
    }
    __syncthreads();

    const int jh = threadIdx.x & 63;   // 64 col-pairs
    const int j  = j0 + jh * 2;
    const int r0 = (threadIdx.x >> 6) * 4;   // 4 rows each

    float ax[4] = {0,0,0,0}, ay[4] = {0,0,0,0};
    for (int k = 0; k < HH; k += 4) {
        float2 b0 = *(const float2*)(A + (size_t)(k + 0) * HH + j);
        float2 b1 = *(const float2*)(A + (size_t)(k + 1) * HH + j);
        float2 b2 = *(const float2*)(A + (size_t)(k + 2) * HH + j);
        float2 b3 = *(const float2*)(A + (size_t)(k + 3) * HH + j);
#pragma unroll
        for (int r = 0; r < 4; r++) {
            float4 av = *(const float4*)(&As[r0 + r][k]);
            ax[r] = fmaf(av.x, b0.x, ax[r]); ax[r] = fmaf(av.y, b1.x, ax[r]);
            ax[r] = fmaf(av.z, b2.x, ax[r]); ax[r] = fmaf(av.w, b3.x, ax[r]);
            ay[r] = fmaf(av.x, b0.y, ay[r]); ay[r] = fmaf(av.y, b1.y, ay[r]);
            ay[r] = fmaf(av.z, b2.y, ay[r]); ay[r] = fmaf(av.w, b3.y, ay[r]);
        }
    }
#pragma unroll
    for (int r = 0; r < 4; r++) {
        float2 o = make_float2(ax[r], ay[r]);
        *(float2*)(Out + (size_t)(a0 + r0 + r) * HH + j) = o;
    }
}

// --------------------------------------------------------- Kogge-Stone ------
// Gout[c] = Gin[c] + Gin[c-s] @ P^T   (P = W^(CK*2^r)), copy for c < s.
// grid (2, NC): col-half x c. block 256.
__global__ __launch_bounds__(256) void ks_kernel(
    const float* __restrict__ Gin, float* __restrict__ Gout,
    const float* __restrict__ P, int sft)
{
    const int c  = blockIdx.y;
    const int q  = blockIdx.x;
    const int j0 = q * 256;
    const int tid = threadIdx.x;

    if (c < sft) {   // copy this col-slice
        const float4* src = (const float4*)(Gin + (size_t)c * NN * HH);
        float4* dst = (float4*)(Gout + (size_t)c * NN * HH);
#pragma unroll
        for (int r = 0; r < 4; r++) {
            int idx = tid + r * 256;          // 0..1023
            int n = idx >> 6, f = idx & 63;
            dst[n * 128 + (j0 >> 2) + f] = src[n * 128 + (j0 >> 2) + f];
        }
        return;
    }

    __shared__ __align__(16) float hs[NN][HH];   // 32 KB = Gin[c-sft]
    {
        const float4* src = (const float4*)(Gin + (size_t)(c - sft) * NN * HH);
        float4* d = (float4*)hs;
#pragma unroll
        for (int r = 0; r < 8; r++) d[tid + r * 256] = src[tid + r * 256];
    }
    __syncthreads();

    const int jh = tid & 127;     // 128 col-pairs -> 256 cols
    const int j  = j0 + jh * 2;
    const int n0 = (tid >> 7) * 8;

    float ax[8] = {0,0,0,0,0,0,0,0}, ay[8] = {0,0,0,0,0,0,0,0};
    const float* P0 = P + (size_t)(j + 0) * HH;
    const float* P1 = P + (size_t)(j + 1) * HH;
    for (int k = 0; k < HH; k += 4) {
        float4 p0 = *(const float4*)(P0 + k);
        float4 p1 = *(const float4*)(P1 + k);
#pragma unroll
        for (int a = 0; a < 8; a++) {
            float4 hv = *(const float4*)(&hs[n0 + a][k]);
            ax[a] = fmaf(hv.x, p0.x, ax[a]); ax[a] = fmaf(hv.y, p0.y, ax[a]);
            ax[a] = fmaf(hv.z, p0.z, ax[a]); ax[a] = fmaf(hv.w, p0.w, ax[a]);
            ay[a] = fmaf(hv.x, p1.x, ay[a]); ay[a] = fmaf(hv.y, p1.y, ay[a]);
            ay[a] = fmaf(hv.z, p1.z, ay[a]); ay[a] = fmaf(hv.w, p1.w, ay[a]);
        }
    }
#pragma unroll
    for (int a = 0; a < 8; a++) {
        const size_t base = (size_t)c * NN * HH + (size_t)(n0 + a) * HH + j;
        float2 gv = *(const float2*)(Gin + base);
        *(float2*)(Gout + base) = make_float2(gv.x + ax[a], gv.y + ay[a]);
    }
}

// ------------------------------------------------------------- launch -------
extern "C" void kernel_launch(void* const* d_in, const int* in_sizes, int n_in,
                              void* d_out, int out_size, void* d_ws, size_t ws_size,
                              hipStream_t stream)
{
    const float* x    = (const float*)d_in[0];
    const float* ini  = (const float*)d_in[1];
    const float* Wi   = (const float*)d_in[2];
    const float* bi   = (const float*)d_in[3];
    const float* Whh  = (const float*)d_in[4];
    float* out   = (float*)d_out;
    float* halfB = out + NTH;
    // W-powers live in the tail of half A: written/read only before phase 3,
    // then overwritten by the final output. 11 MB.
    float* mats  = out + NTH - (long)NMATS * HH * HH;
    // Kogge-Stone ping-pong buffers in workspace: 2 * 8 MB.
    float* G0 = (float*)d_ws;
    float* G1 = G0 + (size_t)NC * NN * HH;

    // 0) shifted input projection -> half B
    proj_kernel<<<dim3(TT / 32, HH / 128, NN), 256, 0, stream>>>(x, Wi, bi, halfB);

    // 1) chunk-local scans -> z_c in G0
    phase_kernel<1><<<dim3(NC), 256, 0, stream>>>(Whh, halfB, ini, nullptr, G0, nullptr);

    // 2) powers W^2 .. W^2048
    sq_kernel<<<dim3(4, 32), 256, 0, stream>>>(Whh, mats);
    for (int i = 1; i < NMATS; i++)
        sq_kernel<<<dim3(4, 32), 256, 0, stream>>>(mats + (size_t)(i - 1) * HH * HH,
                                                   mats + (size_t)i * HH * HH);

    // 3) Kogge-Stone over 256 boundary states (round r uses W^(16*2^r) = mats[3+r])
    for (int r = 0; r < 8; r++) {
        const float* src = (r & 1) ? G1 : G0;
        float* dst       = (r & 1) ? G0 : G1;
        ks_kernel<<<dim3(2, NC), 256, 0, stream>>>(src, dst,
                                                   mats + (size_t)(3 + r) * HH * HH,
                                                   1 << r);
    }
    // after 8 rounds the result is back in G0

    // 4) chunk re-scan from true boundaries, write both halves
    phase_kernel<3><<<dim3(NC), 256, 0, stream>>>(Whh, halfB, ini, G0, nullptr, out);
}